// Round 1
// baseline (2765.437 us; speedup 1.0000x reference)
//
#include <hip/hip_runtime.h>

namespace {

constexpr int   NPIX  = 16384;        // 128*128
constexpr int   NH    = 8;
constexpr int   NB    = 4;
constexpr int   HD    = 512;          // H*D
constexpr float EPSV  = 1e-5f;
constexpr float INV_D = 1.0f / 64.0f;
constexpr float INV_N = 1.0f / 16384.0f;

// ---------------------------------------------------------------------------
// K1: per (chunk, head, batch) block: project K,V for 1024/nc... chunk pixels,
// LayerNorm K, accumulate partial kv[64][64] into ws.
// Weight columns live in VGPRs (thread t owns column j=t&63 of BOTH Wk and Wv).
// v rows are read wave-uniform from global (broadcast; wave g owns pixels g*8..+8).
// ---------------------------------------------------------------------------
__global__ __launch_bounds__(256, 2)
void k1_kv_partial(const float* __restrict__ v,
                   const float* __restrict__ Wk, const float* __restrict__ bk,
                   const float* __restrict__ Wv, const float* __restrict__ bv,
                   const float* __restrict__ lng, const float* __restrict__ lnb,
                   float* __restrict__ part, int nblk)
{
    const int nc = blockIdx.x;
    const int h  = blockIdx.y;
    const int b  = blockIdx.z;
    const int t  = threadIdx.x;

    const int chunk  = NPIX / nblk;
    const int ntiles = chunk / 32;
    const int pix_base = b * NPIX + nc * chunk;

    __shared__ float stage[32][132];   // [pixel][K cols 0..63 | V cols 64..127], padded

    const int j = t & 63;
    const int g = t >> 6;              // wave id

    float wk[64], wv[64];
#pragma unroll
    for (int c = 0; c < 64; ++c) {
        wk[c] = Wk[c * HD + h * 64 + j];
        wv[c] = Wv[c * HD + h * 64 + j];
    }
    const float bkj = bk[h * 64 + j];
    const float bvj = bv[h * 64 + j];

    // LN gamma/beta for this thread's LN slice (p=t>>3, cols (t&7)*8..+8)
    float lg[8], lb[8];
    {
        const int c0 = (t & 7) * 8;
#pragma unroll
        for (int i = 0; i < 8; ++i) {
            lg[i] = lng[h * 64 + c0 + i];
            lb[i] = lnb[h * 64 + c0 + i];
        }
    }

    float acc[16];
#pragma unroll
    for (int i = 0; i < 16; ++i) acc[i] = 0.0f;

    for (int tile = 0; tile < ntiles; ++tile) {
        // ---- projection: 8 pixels per thread, columns j (K) and j (V) ----
        {
            const int pbase = pix_base + tile * 32 + g * 8;
            for (int p = 0; p < 8; ++p) {
                const float4* vr =
                    reinterpret_cast<const float4*>(v + (size_t)(pbase + p) * 64);
                float aK = bkj, aV = bvj;
#pragma unroll
                for (int cq = 0; cq < 16; ++cq) {
                    const float4 v4 = vr[cq];
                    aK = fmaf(v4.x, wk[4*cq+0], aK);
                    aV = fmaf(v4.x, wv[4*cq+0], aV);
                    aK = fmaf(v4.y, wk[4*cq+1], aK);
                    aV = fmaf(v4.y, wv[4*cq+1], aV);
                    aK = fmaf(v4.z, wk[4*cq+2], aK);
                    aV = fmaf(v4.z, wv[4*cq+2], aV);
                    aK = fmaf(v4.w, wk[4*cq+3], aK);
                    aV = fmaf(v4.w, wv[4*cq+3], aV);
                }
                stage[g*8 + p][j]      = aK;
                stage[g*8 + p][64 + j] = aV;
            }
        }
        __syncthreads();

        // ---- LayerNorm on K: 8 threads per pixel, 8 cols each ----
        {
            const int p  = t >> 3;
            const int c0 = (t & 7) * 8;
            float x[8];
            float s1 = 0.0f, s2 = 0.0f;
#pragma unroll
            for (int i = 0; i < 8; ++i) {
                x[i] = stage[p][c0 + i];
                s1 += x[i];
                s2 += x[i] * x[i];
            }
#pragma unroll
            for (int m = 1; m < 8; m <<= 1) {
                s1 += __shfl_xor(s1, m);
                s2 += __shfl_xor(s2, m);
            }
            const float mu  = s1 * INV_D;
            const float var = s2 * INV_D - mu * mu;
            const float rs  = rsqrtf(var + EPSV);
#pragma unroll
            for (int i = 0; i < 8; ++i)
                stage[p][c0 + i] = (x[i] - mu) * rs * lg[i] + lb[i];
        }
        __syncthreads();

        // ---- accumulate kv: 4x4 register tile per thread ----
        {
            const int r0 = (t >> 4) * 4;
            const int c0 = (t & 15) * 4;
#pragma unroll 8
            for (int p = 0; p < 32; ++p) {
                const float4 k4 = *reinterpret_cast<const float4*>(&stage[p][r0]);
                const float4 v4 = *reinterpret_cast<const float4*>(&stage[p][64 + c0]);
                const float kk[4] = {k4.x, k4.y, k4.z, k4.w};
                const float vv[4] = {v4.x, v4.y, v4.z, v4.w};
#pragma unroll
                for (int ri = 0; ri < 4; ++ri)
#pragma unroll
                    for (int ci = 0; ci < 4; ++ci)
                        acc[ri*4 + ci] = fmaf(kk[ri], vv[ci], acc[ri*4 + ci]);
            }
        }
        __syncthreads();
    }

    // write partial kv
    {
        const int r0 = (t >> 4) * 4;
        const int c0 = (t & 15) * 4;
        float* dst = part + ((size_t)((b * NH + h) * nblk + nc)) * 4096;
#pragma unroll
        for (int ri = 0; ri < 4; ++ri) {
            float4 o = make_float4(acc[ri*4+0], acc[ri*4+1], acc[ri*4+2], acc[ri*4+3]);
            *reinterpret_cast<float4*>(dst + (r0 + ri) * 64 + c0) = o;
        }
    }
}

// ---------------------------------------------------------------------------
// K2: per (h, b): reduce kv partials, M = (1/n) * kv @ Wo_h, store TRANSPOSED
// MT[e][d] so K3's reduction over d reads contiguous float4s.
// ---------------------------------------------------------------------------
__global__ __launch_bounds__(256, 2)
void k2_reduce_M(const float* __restrict__ part, const float* __restrict__ Wo,
                 float* __restrict__ MT, int nblk)
{
    const int h = blockIdx.x;
    const int b = blockIdx.y;
    const int t = threadIdx.x;

    __shared__ float kvs[64][65];
    __shared__ float wos[64][64];
    __shared__ float mts[64][65];

    const int r  = t >> 2;            // 0..63
    const int c0 = (t & 3) * 16;      // 0,16,32,48

    // reduce partials: thread owns kv[r][c0..c0+15]
    float a[16];
#pragma unroll
    for (int i = 0; i < 16; ++i) a[i] = 0.0f;
    const float* pb = part + (size_t)(b * NH + h) * nblk * 4096;
    for (int p = 0; p < nblk; ++p) {
        const float* src = pb + (size_t)p * 4096 + r * 64 + c0;
#pragma unroll
        for (int q = 0; q < 4; ++q) {
            const float4 x = *reinterpret_cast<const float4*>(src + 4*q);
            a[4*q+0] += x.x; a[4*q+1] += x.y; a[4*q+2] += x.z; a[4*q+3] += x.w;
        }
    }
#pragma unroll
    for (int i = 0; i < 16; ++i) kvs[r][c0 + i] = a[i];

    // stage Wo_h
#pragma unroll
    for (int i = 0; i < 4; ++i) {
        const int lin4 = t + 256 * i;      // float4 index in 64x64
        const int d  = lin4 >> 4;
        const int e4 = lin4 & 15;
        *reinterpret_cast<float4*>(&wos[d][e4*4]) =
            *reinterpret_cast<const float4*>(Wo + ((size_t)(h*64) + d) * 64 + e4*4);
    }
    __syncthreads();

    // M[r][e0..] = sum_d kv[r][d] * Wo[d][e]
    float m[16];
#pragma unroll
    for (int i = 0; i < 16; ++i) m[i] = 0.0f;
    for (int d = 0; d < 64; ++d) {
        const float kr = kvs[r][d];
#pragma unroll
        for (int q = 0; q < 4; ++q) {
            const float4 w4 = *reinterpret_cast<const float4*>(&wos[d][c0 + 4*q]);
            m[4*q+0] = fmaf(kr, w4.x, m[4*q+0]);
            m[4*q+1] = fmaf(kr, w4.y, m[4*q+1]);
            m[4*q+2] = fmaf(kr, w4.z, m[4*q+2]);
            m[4*q+3] = fmaf(kr, w4.w, m[4*q+3]);
        }
    }
    // transpose via LDS
#pragma unroll
    for (int i = 0; i < 16; ++i) mts[c0 + i][r] = m[i];
    __syncthreads();

    // coalesced transposed store with 1/n folded in
    {
        const int e  = t >> 2;
        const int d0 = (t & 3) * 16;
        float* dst = MT + (size_t)(b * NH + h) * 4096 + e * 64 + d0;
#pragma unroll
        for (int q = 0; q < 4; ++q) {
            float4 o = make_float4(mts[e][d0 + 4*q + 0] * INV_N,
                                   mts[e][d0 + 4*q + 1] * INV_N,
                                   mts[e][d0 + 4*q + 2] * INV_N,
                                   mts[e][d0 + 4*q + 3] * INV_N);
            *reinterpret_cast<float4*>(dst + 4*q) = o;
        }
    }
}

// ---------------------------------------------------------------------------
// K3: per (64-pixel block, batch): for each head-pair, project Q (2 weight
// columns per thread, in VGPRs), LayerNorm, accumulate out += q . MT rows.
// MT read directly from global (512 KB total -> L2-resident).
// ---------------------------------------------------------------------------
__global__ __launch_bounds__(256, 2)
void k3_attn_out(const float* __restrict__ v,
                 const float* __restrict__ Wq, const float* __restrict__ bq,
                 const float* __restrict__ lng, const float* __restrict__ lnb,
                 const float* __restrict__ MT,
                 const float* __restrict__ Wob,
                 float* __restrict__ out)
{
    const int blk = blockIdx.x;        // 0..255
    const int b   = blockIdx.y;
    const int t   = threadIdx.x;
    const int pix0 = b * NPIX + blk * 64;

    __shared__ float stage[2][64][68]; // [head-in-pair][pixel][col]

    const int j  = t & 63;
    const int g  = t >> 6;
    const int pg = t >> 4;             // 0..15 -> pixels pg*4..+4
    const int e0 = (t & 15) * 4;

    float acc[4][4];
#pragma unroll
    for (int i = 0; i < 4; ++i)
#pragma unroll
        for (int k = 0; k < 4; ++k) acc[i][k] = 0.0f;

    for (int hp = 0; hp < 4; ++hp) {
        const int h0 = hp * 2;

        // weight columns for both heads of the pair
        float wqA[64], wqB[64];
#pragma unroll
        for (int c = 0; c < 64; ++c) {
            wqA[c] = Wq[c * HD + h0 * 64 + j];
            wqB[c] = Wq[c * HD + (h0 + 1) * 64 + j];
        }
        const float bA = bq[h0 * 64 + j];
        const float bB = bq[(h0 + 1) * 64 + j];

        // projection: wave g owns pixels g*16..+16; thread computes col j for 2 heads
        for (int p = 0; p < 16; ++p) {
            const int pp = g * 16 + p;
            const float4* vr =
                reinterpret_cast<const float4*>(v + (size_t)(pix0 + pp) * 64);
            float aA = bA, aB = bB;
#pragma unroll
            for (int cq = 0; cq < 16; ++cq) {
                const float4 v4 = vr[cq];
                aA = fmaf(v4.x, wqA[4*cq+0], aA);
                aB = fmaf(v4.x, wqB[4*cq+0], aB);
                aA = fmaf(v4.y, wqA[4*cq+1], aA);
                aB = fmaf(v4.y, wqB[4*cq+1], aB);
                aA = fmaf(v4.z, wqA[4*cq+2], aA);
                aB = fmaf(v4.z, wqB[4*cq+2], aB);
                aA = fmaf(v4.w, wqA[4*cq+3], aA);
                aB = fmaf(v4.w, wqB[4*cq+3], aB);
            }
            stage[0][pp][j] = aA;
            stage[1][pp][j] = aB;
        }
        __syncthreads();

        // LayerNorm both heads: thread -> (pixel,p-head) pair, half row each
        {
            const int ph = t >> 1;         // 0..127
            const int hh = ph & 1;
            const int p  = ph >> 1;        // 0..63
            const int c0 = (t & 1) * 32;
            float x[32];
            float s1 = 0.0f, s2 = 0.0f;
#pragma unroll
            for (int i = 0; i < 32; ++i) {
                x[i] = stage[hh][p][c0 + i];
                s1 += x[i];
                s2 += x[i] * x[i];
            }
            s1 += __shfl_xor(s1, 1);
            s2 += __shfl_xor(s2, 1);
            const float mu  = s1 * INV_D;
            const float var = s2 * INV_D - mu * mu;
            const float rs  = rsqrtf(var + EPSV);
            const float* gg = lng + (h0 + hh) * 64 + c0;
            const float* bb = lnb + (h0 + hh) * 64 + c0;
#pragma unroll
            for (int i = 0; i < 32; ++i)
                stage[hh][p][c0 + i] = (x[i] - mu) * rs * gg[i] + bb[i];
        }
        __syncthreads();

        // accumulate out[p][e] += sum_d q[p][d] * MT[e][d]
#pragma unroll
        for (int hh = 0; hh < 2; ++hh) {
            const float* mt = MT + (size_t)(b * NH + h0 + hh) * 4096;
#pragma unroll 4
            for (int dq = 0; dq < 16; ++dq) {
                float4 q4[4];
#pragma unroll
                for (int pi = 0; pi < 4; ++pi)
                    q4[pi] = *reinterpret_cast<const float4*>(
                        &stage[hh][pg*4 + pi][4*dq]);
#pragma unroll
                for (int ei = 0; ei < 4; ++ei) {
                    const float4 m4 = *reinterpret_cast<const float4*>(
                        mt + (e0 + ei) * 64 + 4*dq);
#pragma unroll
                    for (int pi = 0; pi < 4; ++pi) {
                        acc[pi][ei] = fmaf(q4[pi].x, m4.x, acc[pi][ei]);
                        acc[pi][ei] = fmaf(q4[pi].y, m4.y, acc[pi][ei]);
                        acc[pi][ei] = fmaf(q4[pi].z, m4.z, acc[pi][ei]);
                        acc[pi][ei] = fmaf(q4[pi].w, m4.w, acc[pi][ei]);
                    }
                }
            }
        }
        __syncthreads();
    }

    // epilogue: add Wo_b/n, store
    {
        const float4 wb = *reinterpret_cast<const float4*>(Wob + e0);
#pragma unroll
        for (int pi = 0; pi < 4; ++pi) {
            const int pp = pg * 4 + pi;
            float4 o;
            o.x = acc[pi][0] + wb.x * INV_N;
            o.y = acc[pi][1] + wb.y * INV_N;
            o.z = acc[pi][2] + wb.z * INV_N;
            o.w = acc[pi][3] + wb.w * INV_N;
            *reinterpret_cast<float4*>(out + (size_t)(pix0 + pp) * 64 + e0) = o;
        }
    }
}

} // namespace

extern "C" void kernel_launch(void* const* d_in, const int* in_sizes, int n_in,
                              void* d_out, int out_size, void* d_ws, size_t ws_size,
                              hipStream_t stream)
{
    const float* v     = (const float*)d_in[0];
    const float* Wq_w  = (const float*)d_in[1];
    const float* Wq_b  = (const float*)d_in[2];
    const float* Wk_w  = (const float*)d_in[3];
    const float* Wk_b  = (const float*)d_in[4];
    const float* Wv_w  = (const float*)d_in[5];
    const float* Wv_b  = (const float*)d_in[6];
    const float* lnq_g = (const float*)d_in[7];
    const float* lnq_b = (const float*)d_in[8];
    const float* lnk_g = (const float*)d_in[9];
    const float* lnk_b = (const float*)d_in[10];
    const float* Wo_w  = (const float*)d_in[11];
    const float* Wo_b  = (const float*)d_in[12];
    float* out = (float*)d_out;

    // adaptive chunk count so partials + M fit in ws
    int nblk = 16;
    while (nblk > 1 &&
           (size_t)NB * NH * (nblk + 1) * 4096 * sizeof(float) > ws_size)
        nblk >>= 1;

    float* part = (float*)d_ws;
    float* MT   = part + (size_t)NB * NH * nblk * 4096;

    k1_kv_partial<<<dim3(nblk, NH, NB), 256, 0, stream>>>(
        v, Wk_w, Wk_b, Wv_w, Wv_b, lnk_g, lnk_b, part, nblk);
    k2_reduce_M<<<dim3(NH, NB), 256, 0, stream>>>(part, Wo_w, MT, nblk);
    k3_attn_out<<<dim3(NPIX / 64, NB), 256, 0, stream>>>(
        v, Wq_w, Wq_b, lnq_g, lnq_b, MT, Wo_b, out);
}

// Round 2
// 187.389 us; speedup vs baseline: 14.7577x; 14.7577x over previous
//
#include <hip/hip_runtime.h>

typedef __attribute__((ext_vector_type(8))) short bhalf8;
typedef __attribute__((ext_vector_type(4))) float f32x4;

#define MFMA_BF16 __builtin_amdgcn_mfma_f32_16x16x32_bf16

namespace {

constexpr int   NPIX  = 16384;
constexpr float EPSV  = 1e-5f;
constexpr float INV64 = 1.0f / 64.0f;
constexpr float INV_N = 1.0f / 16384.0f;

__device__ __forceinline__ unsigned short f2bf(float f) {
    unsigned int u = __builtin_bit_cast(unsigned int, f);
    u += 0x7fffu + ((u >> 16) & 1u);          // round-to-nearest-even
    return (unsigned short)(u >> 16);
}

// ---------------------------------------------------------------------------
// K0: vsum[b][c] = sum_p v[b,p,c]   (for the beta_k * Sv fold in K2)
// ---------------------------------------------------------------------------
__global__ void k0_vsum(const float* __restrict__ v, float* __restrict__ vsum)
{
    const int slab = blockIdx.x, b = blockIdx.y, t = threadIdx.x;
    const int c = t & 63, po = t >> 6;
    const float* src = v + ((size_t)b * NPIX + slab * 256 + po * 64) * 64 + c;
    float s = 0.f;
#pragma unroll 8
    for (int i = 0; i < 64; ++i) s += src[(size_t)i * 64];
    __shared__ float red[4][64];
    red[po][c] = s;
    __syncthreads();
    if (t < 64) {
        float x = red[0][t] + red[1][t] + red[2][t] + red[3][t];
        atomicAdd(vsum + b * 64 + t, x);
    }
}

// ---------------------------------------------------------------------------
// K1: kvG[b,h] += K̂'^T V  (pre-gamma/beta LayerNorm'd K, bias'd V), MFMA.
// Block = (chunk,h,b), 4 waves; wave owns 256 px, loops 8 subtiles of 32 px.
// Wave-private LDS zones; block LDS-reduce then atomics.
// All transposed products: X^T = W^T * v^T so C-frag row = feature dim.
// ---------------------------------------------------------------------------
__global__ __launch_bounds__(256, 2)
void k1_kv(const float* __restrict__ v,  const float* __restrict__ Wk,
           const float* __restrict__ bk, const float* __restrict__ Wv,
           const float* __restrict__ bv, float* __restrict__ kvG)
{
    const int ch = blockIdx.x, h = blockIdx.y, b = blockIdx.z;
    const int t = threadIdx.x;
    const int w = t >> 6, l = t & 63, g = l >> 4, m16 = l & 15;

    __shared__ float kvred[4][4096];                       // 64 KB, aliased zones
    char* zone = reinterpret_cast<char*>(&kvred[0][0]) + w * 14848;
    unsigned short* vz  = reinterpret_cast<unsigned short*>(zone);          // [32][72] bf16
    unsigned short* ktz = reinterpret_cast<unsigned short*>(zone + 4608);   // [64][40] bf16
    unsigned short* vtz = reinterpret_cast<unsigned short*>(zone + 9728);   // [64][40] bf16

    // Weight A-fragments (W^T): lane holds W[c = 32ks+8g+j][h*64 + 16mt + m16]
    bhalf8 wkf[4][2], wvf[4][2];
    const int wcol = h * 64 + m16;
#pragma unroll
    for (int mt = 0; mt < 4; ++mt)
#pragma unroll
      for (int ks = 0; ks < 2; ++ks)
#pragma unroll
        for (int j = 0; j < 8; ++j) {
            const int c = 32 * ks + 8 * g + j;
            wkf[mt][ks][j] = (short)f2bf(Wk[c * 512 + wcol + 16 * mt]);
            wvf[mt][ks][j] = (short)f2bf(Wv[c * 512 + wcol + 16 * mt]);
        }
    float bkr[4][4], bvr[4][4];
#pragma unroll
    for (int mt = 0; mt < 4; ++mt)
#pragma unroll
      for (int q = 0; q < 4; ++q) {
          const int d = 16 * mt + 4 * g + q;
          bkr[mt][q] = bk[h * 64 + d];
          bvr[mt][q] = bv[h * 64 + d];
      }

    f32x4 kv[4][4];
#pragma unroll
    for (int i = 0; i < 4; ++i)
#pragma unroll
      for (int j2 = 0; j2 < 4; ++j2) kv[i][j2] = f32x4{0.f, 0.f, 0.f, 0.f};

    const float* vbase = v + ((size_t)b * NPIX + ch * 1024 + w * 256) * 64;
    const int sp = l >> 1, sh = l & 1;

    for (int s = 0; s < 8; ++s) {
        // ---- stage v subtile (32 px x 64 c) to LDS as bf16 ----
        {
            const float4* src = reinterpret_cast<const float4*>(
                vbase + (size_t)(s * 32 + sp) * 64 + sh * 32);
            unsigned short* dst = vz + sp * 72 + sh * 32;
#pragma unroll
            for (int qq = 0; qq < 8; ++qq) {
                float4 x = src[qq];
                ushort4 o;
                o.x = f2bf(x.x); o.y = f2bf(x.y); o.z = f2bf(x.z); o.w = f2bf(x.w);
                *reinterpret_cast<ushort4*>(dst + qq * 4) = o;
            }
        }
        __builtin_amdgcn_sched_barrier(0);
        // ---- v^T B-fragments: lane reads v[p = 16nt+m16][c = 32ks+8g .. +8] ----
        bhalf8 vf[2][2];
#pragma unroll
        for (int nt = 0; nt < 2; ++nt)
#pragma unroll
          for (int ks = 0; ks < 2; ++ks)
            vf[nt][ks] = *reinterpret_cast<const bhalf8*>(
                vz + (16 * nt + m16) * 72 + 32 * ks + 8 * g);

        // ---- V^T projection: bias + store to VT lds [e][p] ----
#pragma unroll
        for (int mt = 0; mt < 4; ++mt)
#pragma unroll
          for (int nt = 0; nt < 2; ++nt) {
              f32x4 a = {0.f, 0.f, 0.f, 0.f};
              a = MFMA_BF16(wvf[mt][0], vf[nt][0], a, 0, 0, 0);
              a = MFMA_BF16(wvf[mt][1], vf[nt][1], a, 0, 0, 0);
#pragma unroll
              for (int q = 0; q < 4; ++q)
                  vtz[(16 * mt + 4 * g + q) * 40 + 16 * nt + m16] =
                      f2bf(a[q] + bvr[mt][q]);
          }

        // ---- K^T projection (+bias), then LayerNorm over d, store KT [d][p] ----
        f32x4 pa[4][2];
#pragma unroll
        for (int mt = 0; mt < 4; ++mt)
#pragma unroll
          for (int nt = 0; nt < 2; ++nt) {
              f32x4 a = {0.f, 0.f, 0.f, 0.f};
              a = MFMA_BF16(wkf[mt][0], vf[nt][0], a, 0, 0, 0);
              a = MFMA_BF16(wkf[mt][1], vf[nt][1], a, 0, 0, 0);
#pragma unroll
              for (int q = 0; q < 4; ++q) a[q] += bkr[mt][q];
              pa[mt][nt] = a;
          }
#pragma unroll
        for (int nt = 0; nt < 2; ++nt) {
            float s1 = 0.f, s2 = 0.f;
#pragma unroll
            for (int mt = 0; mt < 4; ++mt)
#pragma unroll
              for (int q = 0; q < 4; ++q) {
                  float x = pa[mt][nt][q]; s1 += x; s2 = fmaf(x, x, s2);
              }
            s1 += __shfl_xor(s1, 16, 64); s1 += __shfl_xor(s1, 32, 64);
            s2 += __shfl_xor(s2, 16, 64); s2 += __shfl_xor(s2, 32, 64);
            const float mu = s1 * INV64;
            const float rs = rsqrtf(fmaxf(s2 * INV64 - mu * mu, 0.f) + EPSV);
#pragma unroll
            for (int mt = 0; mt < 4; ++mt)
#pragma unroll
              for (int q = 0; q < 4; ++q)
                  ktz[(16 * mt + 4 * g + q) * 40 + 16 * nt + m16] =
                      f2bf((pa[mt][nt][q] - mu) * rs);
        }
        __builtin_amdgcn_sched_barrier(0);

        // ---- kv += K̂^T · V  (contraction over 32 px, single k-step) ----
        bhalf8 ka[4], vb2[4];
#pragma unroll
        for (int mt = 0; mt < 4; ++mt)
            ka[mt] = *reinterpret_cast<const bhalf8*>(ktz + (16 * mt + m16) * 40 + 8 * g);
#pragma unroll
        for (int nt = 0; nt < 4; ++nt)
            vb2[nt] = *reinterpret_cast<const bhalf8*>(vtz + (16 * nt + m16) * 40 + 8 * g);
#pragma unroll
        for (int mt = 0; mt < 4; ++mt)
#pragma unroll
          for (int nt = 0; nt < 4; ++nt)
              kv[mt][nt] = MFMA_BF16(ka[mt], vb2[nt], kv[mt][nt], 0, 0, 0);
        __builtin_amdgcn_sched_barrier(0);
    }

    // ---- block reduce across 4 waves, then coalesced atomics ----
    __syncthreads();
#pragma unroll
    for (int mt = 0; mt < 4; ++mt)
#pragma unroll
      for (int nt = 0; nt < 4; ++nt)
#pragma unroll
        for (int q = 0; q < 4; ++q)
            kvred[w][(16 * mt + 4 * g + q) * 64 + 16 * nt + m16] = kv[mt][nt][q];
    __syncthreads();
    float* dstg = kvG + ((size_t)(b * 8 + h)) * 4096;
#pragma unroll
    for (int i = 0; i < 16; ++i) {
        const int idx = i * 256 + t;
        const float srd = kvred[0][idx] + kvred[1][idx] + kvred[2][idx] + kvred[3][idx];
        atomicAdd(dstg + idx, srd);
    }
}

// ---------------------------------------------------------------------------
// K2: per (h,b): kvF = gamma_k*kvG + beta_k (x) Sv ;  M = kvF @ Wo_h ;
//     MT'[e][d] = gamma_q[d]*M[d][e]/n (bf16) ; cbeta[b] += beta_q^T M / n (+Wo_b/n)
// ---------------------------------------------------------------------------
__global__ void k2_mix(const float* __restrict__ kvG,  const float* __restrict__ vsum,
                       const float* __restrict__ Wv,   const float* __restrict__ bv,
                       const float* __restrict__ lnkg, const float* __restrict__ lnkb,
                       const float* __restrict__ lnqg, const float* __restrict__ lnqb,
                       const float* __restrict__ Wo,   const float* __restrict__ Wob,
                       unsigned short* __restrict__ MTp, float* __restrict__ cbeta)
{
    const int h = blockIdx.x, b = blockIdx.y, t = threadIdx.x;
    __shared__ float kvs[64][65], wos[64][65], mts[64][65], Svs[64], us[64];
    const int r = t >> 2, c0 = (t & 3) * 16;
    const float* kg = kvG + ((size_t)(b * 8 + h)) * 4096;
#pragma unroll
    for (int i = 0; i < 16; i += 4) {
        float4 x = *reinterpret_cast<const float4*>(kg + r * 64 + c0 + i);
        kvs[r][c0+i] = x.x; kvs[r][c0+i+1] = x.y; kvs[r][c0+i+2] = x.z; kvs[r][c0+i+3] = x.w;
    }
#pragma unroll
    for (int i = 0; i < 16; i += 4) {
        float4 x = *reinterpret_cast<const float4*>(Wo + ((size_t)(h * 64) + r) * 64 + c0 + i);
        wos[r][c0+i] = x.x; wos[r][c0+i+1] = x.y; wos[r][c0+i+2] = x.z; wos[r][c0+i+3] = x.w;
    }
    if (t < 64) {
        float s = 16384.f * bv[h * 64 + t];
        for (int cc = 0; cc < 64; ++cc)
            s = fmaf(vsum[b * 64 + cc], Wv[cc * 512 + h * 64 + t], s);
        Svs[t] = s;
    }
    __syncthreads();
    {   // kvF in place (each thread touches only its own slice)
        const float gk = lnkg[h * 64 + r], bk2 = lnkb[h * 64 + r];
#pragma unroll
        for (int i = 0; i < 16; ++i)
            kvs[r][c0 + i] = gk * kvs[r][c0 + i] + bk2 * Svs[c0 + i];
    }
    __syncthreads();
    if (t < 64) {   // u[e'] = sum_d beta_q[d] * kvF[d][e']
        float s = 0.f;
        for (int dd = 0; dd < 64; ++dd) s = fmaf(lnqb[h * 64 + dd], kvs[dd][t], s);
        us[t] = s;
    }
    float mrow[16];
#pragma unroll
    for (int i = 0; i < 16; ++i) mrow[i] = 0.f;
    for (int e2 = 0; e2 < 64; ++e2) {
        const float kr = kvs[r][e2];
#pragma unroll
        for (int i = 0; i < 16; ++i) mrow[i] = fmaf(kr, wos[e2][c0 + i], mrow[i]);
    }
    {   // mts[e][d] = gamma_q[d]/n * M[d][e]
        const float gq = lnqg[h * 64 + r] * INV_N;
#pragma unroll
        for (int i = 0; i < 16; ++i) mts[c0 + i][r] = gq * mrow[i];
    }
    __syncthreads();
    if (t < 64) {
        float s = 0.f;
        for (int e2 = 0; e2 < 64; ++e2) s = fmaf(us[e2], wos[e2][t], s);
        atomicAdd(cbeta + b * 64 + t, s * INV_N);
        if (h == 0) atomicAdd(cbeta + b * 64 + t, Wob[t] * INV_N);
    }
    unsigned short* mo = MTp + ((size_t)(b * 8 + h)) * 4096 + r * 64 + c0;
#pragma unroll
    for (int i = 0; i < 16; i += 4) {
        ushort4 o;
        o.x = f2bf(mts[r][c0+i]);   o.y = f2bf(mts[r][c0+i+1]);
        o.z = f2bf(mts[r][c0+i+2]); o.w = f2bf(mts[r][c0+i+3]);
        *reinterpret_cast<ushort4*>(mo + i) = o;
    }
}

// ---------------------------------------------------------------------------
// K3: wave = 32 px, loops 8 heads: Q̂'^T = LN(Wq^T v^T + bq), out^T += M'^T Q̂'^T.
// M'^T read from global (L2-resident bf16). Epilogue adds cbeta (has Wo_b/n).
// ---------------------------------------------------------------------------
__global__ __launch_bounds__(256, 2)
void k3_out(const float* __restrict__ v,  const float* __restrict__ Wq,
            const float* __restrict__ bq, const unsigned short* __restrict__ MTp,
            const float* __restrict__ cbeta, float* __restrict__ out)
{
    const int blk = blockIdx.x, b = blockIdx.y;
    const int t = threadIdx.x, w = t >> 6, l = t & 63, g = l >> 4, m16 = l & 15;

    __shared__ unsigned short smem[4][4608];       // per wave: v [32][72] + QT [32][72]
    unsigned short* vz  = smem[w];
    unsigned short* qtz = smem[w] + 2304;

    const int px0 = blk * 128 + w * 32;
    const float* vbase = v + ((size_t)b * NPIX + px0) * 64;
    const int sp = l >> 1, sh = l & 1;
    {
        const float4* src = reinterpret_cast<const float4*>(vbase + (size_t)sp * 64 + sh * 32);
        unsigned short* dst = vz + sp * 72 + sh * 32;
#pragma unroll
        for (int qq = 0; qq < 8; ++qq) {
            float4 x = src[qq];
            ushort4 o;
            o.x = f2bf(x.x); o.y = f2bf(x.y); o.z = f2bf(x.z); o.w = f2bf(x.w);
            *reinterpret_cast<ushort4*>(dst + qq * 4) = o;
        }
    }
    __builtin_amdgcn_sched_barrier(0);
    bhalf8 vf[2][2];
#pragma unroll
    for (int nt = 0; nt < 2; ++nt)
#pragma unroll
      for (int ks = 0; ks < 2; ++ks)
        vf[nt][ks] = *reinterpret_cast<const bhalf8*>(
            vz + (16 * nt + m16) * 72 + 32 * ks + 8 * g);

    f32x4 outa[4][2];
#pragma unroll
    for (int i = 0; i < 4; ++i)
#pragma unroll
      for (int j2 = 0; j2 < 2; ++j2) outa[i][j2] = f32x4{0.f, 0.f, 0.f, 0.f};

    for (int h = 0; h < 8; ++h) {
        bhalf8 wqf[4][2];
        float bqr[4][4];
        const int wcol = h * 64 + m16;
#pragma unroll
        for (int mt = 0; mt < 4; ++mt)
#pragma unroll
          for (int ks = 0; ks < 2; ++ks)
#pragma unroll
            for (int j = 0; j < 8; ++j) {
                const int c = 32 * ks + 8 * g + j;
                wqf[mt][ks][j] = (short)f2bf(Wq[c * 512 + wcol + 16 * mt]);
            }
#pragma unroll
        for (int mt = 0; mt < 4; ++mt)
#pragma unroll
          for (int q = 0; q < 4; ++q) bqr[mt][q] = bq[h * 64 + 16 * mt + 4 * g + q];

        bhalf8 mf[4][2];
        const unsigned short* mtb = MTp + ((size_t)(b * 8 + h)) * 4096;
#pragma unroll
        for (int mt = 0; mt < 4; ++mt)
#pragma unroll
          for (int ks = 0; ks < 2; ++ks)
            mf[mt][ks] = *reinterpret_cast<const bhalf8*>(
                mtb + (16 * mt + m16) * 64 + 32 * ks + 8 * g);

        // Q^T projection + bias
        f32x4 qa[4][2];
#pragma unroll
        for (int mt = 0; mt < 4; ++mt)
#pragma unroll
          for (int nt = 0; nt < 2; ++nt) {
              f32x4 a = {0.f, 0.f, 0.f, 0.f};
              a = MFMA_BF16(wqf[mt][0], vf[nt][0], a, 0, 0, 0);
              a = MFMA_BF16(wqf[mt][1], vf[nt][1], a, 0, 0, 0);
#pragma unroll
              for (int q = 0; q < 4; ++q) a[q] += bqr[mt][q];
              qa[mt][nt] = a;
          }
        // LN over d (no gamma/beta: folded into M' and cbeta); store QT [p][d]
#pragma unroll
        for (int nt = 0; nt < 2; ++nt) {
            float s1 = 0.f, s2 = 0.f;
#pragma unroll
            for (int mt = 0; mt < 4; ++mt)
#pragma unroll
              for (int q = 0; q < 4; ++q) {
                  float x = qa[mt][nt][q]; s1 += x; s2 = fmaf(x, x, s2);
              }
            s1 += __shfl_xor(s1, 16, 64); s1 += __shfl_xor(s1, 32, 64);
            s2 += __shfl_xor(s2, 16, 64); s2 += __shfl_xor(s2, 32, 64);
            const float mu = s1 * INV64;
            const float rs = rsqrtf(fmaxf(s2 * INV64 - mu * mu, 0.f) + EPSV);
#pragma unroll
            for (int mt = 0; mt < 4; ++mt)
#pragma unroll
              for (int q = 0; q < 4; ++q)
                  qtz[(16 * nt + m16) * 72 + 16 * mt + 4 * g + q] =
                      f2bf((qa[mt][nt][q] - mu) * rs);
        }
        __builtin_amdgcn_sched_barrier(0);
        bhalf8 qb[2][2];
#pragma unroll
        for (int nt = 0; nt < 2; ++nt)
#pragma unroll
          for (int ks = 0; ks < 2; ++ks)
            qb[nt][ks] = *reinterpret_cast<const bhalf8*>(
                qtz + (16 * nt + m16) * 72 + 32 * ks + 8 * g);
#pragma unroll
        for (int mt = 0; mt < 4; ++mt)
#pragma unroll
          for (int nt = 0; nt < 2; ++nt) {
              outa[mt][nt] = MFMA_BF16(mf[mt][0], qb[nt][0], outa[mt][nt], 0, 0, 0);
              outa[mt][nt] = MFMA_BF16(mf[mt][1], qb[nt][1], outa[mt][nt], 0, 0, 0);
          }
        __builtin_amdgcn_sched_barrier(0);
    }

    // epilogue: out[p][e] = outT[e][p] + cbeta[b][e]
    float* ob = out + ((size_t)b * NPIX + px0) * 64;
#pragma unroll
    for (int mt = 0; mt < 4; ++mt)
#pragma unroll
      for (int q = 0; q < 4; ++q) {
          const int e = 16 * mt + 4 * g + q;
          const float add = cbeta[b * 64 + e];
#pragma unroll
          for (int nt = 0; nt < 2; ++nt)
              ob[(size_t)(16 * nt + m16) * 64 + e] = outa[mt][nt][q] + add;
      }
}

} // namespace

extern "C" void kernel_launch(void* const* d_in, const int* in_sizes, int n_in,
                              void* d_out, int out_size, void* d_ws, size_t ws_size,
                              hipStream_t stream)
{
    const float* v     = (const float*)d_in[0];
    const float* Wq_w  = (const float*)d_in[1];
    const float* Wq_b  = (const float*)d_in[2];
    const float* Wk_w  = (const float*)d_in[3];
    const float* Wk_b  = (const float*)d_in[4];
    const float* Wv_w  = (const float*)d_in[5];
    const float* Wv_b  = (const float*)d_in[6];
    const float* lnq_g = (const float*)d_in[7];
    const float* lnq_b = (const float*)d_in[8];
    const float* lnk_g = (const float*)d_in[9];
    const float* lnk_b = (const float*)d_in[10];
    const float* Wo_w  = (const float*)d_in[11];
    const float* Wo_b  = (const float*)d_in[12];
    float* out = (float*)d_out;

    float* kvG   = (float*)d_ws;                       // [4][8][64][64] f32
    float* vsum  = kvG + 131072;                       // [4][64]
    float* cbeta = vsum + 256;                         // [4][64]
    unsigned short* MTp = (unsigned short*)(cbeta + 256);  // [4][8][64][64] bf16

    hipMemsetAsync(d_ws, 0, (131072 + 512) * sizeof(float), stream);
    k0_vsum<<<dim3(64, 4), 256, 0, stream>>>(v, vsum);
    k1_kv<<<dim3(16, 8, 4), 256, 0, stream>>>(v, Wk_w, Wk_b, Wv_w, Wv_b, kvG);
    k2_mix<<<dim3(8, 4), 256, 0, stream>>>(kvG, vsum, Wv_w, Wv_b, lnk_g, lnk_b,
                                           lnq_g, lnq_b, Wo_w, Wo_b, MTp, cbeta);
    k3_out<<<dim3(128, 4), 256, 0, stream>>>(v, Wq_w, Wq_b, MTp, cbeta, out);
}

// Round 3
// 178.874 us; speedup vs baseline: 15.4602x; 1.0476x over previous
//
#include <hip/hip_runtime.h>
#include <hip/hip_bf16.h>

typedef __attribute__((ext_vector_type(8))) short bhalf8;
typedef __attribute__((ext_vector_type(4))) float f32x4;

#define MFMA_BF16 __builtin_amdgcn_mfma_f32_16x16x32_bf16

namespace {

constexpr int   NPIX  = 16384;
constexpr float EPSV  = 1e-5f;
constexpr float INV64 = 1.0f / 64.0f;
constexpr float INV_N = 1.0f / 16384.0f;

// ws layout (floats): kv1[4*8*4096] t[4*8*64] vsum[4*64] cbeta[4*64]
// then shorts: wkpk[32768] wvpk[32768] wqpk[32768] wksum[512] mpk[131072]
constexpr int KV1_OFF   = 0;
constexpr int T_OFF     = 131072;
constexpr int VSUM_OFF  = 131072 + 2048;
constexpr int CBETA_OFF = 131072 + 2048 + 256;
constexpr int FZERO_CNT = 131072 + 2048 + 256 + 256;   // floats to zero

__device__ __host__ __forceinline__ unsigned short f2bf(float f) {
    unsigned int u = __builtin_bit_cast(unsigned int, f);
    u += 0x7fffu + ((u >> 16) & 1u);
    return (unsigned short)(u >> 16);
}

union B8 { bhalf8 v; unsigned int u[4]; ushort4 s4[2]; };

__device__ __forceinline__ unsigned int pk2(float a, float b) {
    union { __hip_bfloat162 h; unsigned int u; } x;
    x.h = __float22bfloat162_rn(float2{a, b});
    return x.u;
}

// ---------------------------------------------------------------------------
// k0: vsum[b][c] = sum_p v[b,p,c]  (fp32, coalesced float4)
// ---------------------------------------------------------------------------
__global__ void k0_vsum(const float* __restrict__ v, float* __restrict__ vsum)
{
    const int blk = blockIdx.x, b = blockIdx.y, t = threadIdx.x;
    const int c4 = t & 15, p = t >> 4;
    float4 a = make_float4(0.f, 0.f, 0.f, 0.f);
    const float* base = v + ((size_t)b * NPIX + blk * 128) * 64 + c4 * 4;
#pragma unroll
    for (int i = 0; i < 8; ++i) {
        const float4 x = *reinterpret_cast<const float4*>(base + (size_t)(p * 8 + i) * 64);
        a.x += x.x; a.y += x.y; a.z += x.z; a.w += x.w;
    }
    __shared__ float4 red[16][16];
    red[p][c4] = a;
    __syncthreads();
    if (t < 16) {
        float4 s = red[0][t];
#pragma unroll
        for (int i = 1; i < 16; ++i) {
            const float4 x = red[i][t];
            s.x += x.x; s.y += x.y; s.z += x.z; s.w += x.w;
        }
        atomicAdd(vsum + b * 64 + t * 4 + 0, s.x);
        atomicAdd(vsum + b * 64 + t * 4 + 1, s.y);
        atomicAdd(vsum + b * 64 + t * 4 + 2, s.z);
        atomicAdd(vsum + b * 64 + t * 4 + 3, s.w);
    }
}

// ---------------------------------------------------------------------------
// kpack: pre-pack weight fragments (bf16, one dwordx4 per fragment per lane).
// Fragment element j of lane l=(g,m) for (sub-tile s, ks) = W[32ks+8g+j][h*64+16s+m].
// Also wksum[h][c] = sum_d Wk[c][h*64+d] (bf16) for the s1 row-sum trick.
// ---------------------------------------------------------------------------
__global__ void kpack(const float* __restrict__ Wk, const float* __restrict__ Wv,
                      const float* __restrict__ Wq,
                      unsigned short* __restrict__ wkpk, unsigned short* __restrict__ wvpk,
                      unsigned short* __restrict__ wqpk, unsigned short* __restrict__ wksumb)
{
    const int w = blockIdx.x >> 3, h = blockIdx.x & 7, t = threadIdx.x;
    const float* W = (w == 0) ? Wk : (w == 1) ? Wv : Wq;
    unsigned short* dst = (w == 0) ? wkpk : (w == 1) ? wvpk : wqpk;

#pragma unroll
    for (int i = 0; i < 2; ++i) {
        const int f = t * 2 + i;
        const int nt = (f >> 7) & 3, ks = (f >> 6) & 1, l = f & 63;
        const int g = l >> 4, m = l & 15;
        ushort4 o0, o1;
        unsigned short tmp[8];
#pragma unroll
        for (int j = 0; j < 8; ++j)
            tmp[j] = f2bf(W[(size_t)(32 * ks + 8 * g + j) * 512 + h * 64 + 16 * nt + m]);
        o0 = make_ushort4(tmp[0], tmp[1], tmp[2], tmp[3]);
        o1 = make_ushort4(tmp[4], tmp[5], tmp[6], tmp[7]);
        unsigned short* d = dst + ((size_t)((h * 4 + nt) * 2 + ks)) * 512 + l * 8;
        *reinterpret_cast<ushort4*>(d)     = o0;
        *reinterpret_cast<ushort4*>(d + 4) = o1;
    }
    if (w == 0 && t < 64) {
        float s = 0.f;
        const float* row = Wk + (size_t)t * 512 + h * 64;
#pragma unroll
        for (int d = 0; d < 64; ++d) s += row[d];
        wksumb[h * 64 + t] = f2bf(s);
    }
}

// ---------------------------------------------------------------------------
// k1: per (chunk,h,b): standard-orientation projections (C-layout [px][d]),
// per-pixel LN folded to K~ = rs*K and rank-1 t[e]; kv1 += K~^T V' via MFMA
// with the permuted k-slot map pi(g,j)=16(j>>2)+4g+(j&3)  -> operand fragments
// are the projection outputs' OWN registers. No LDS in the main loop.
// ---------------------------------------------------------------------------
__global__ __launch_bounds__(256, 2)
void k1_kv(const float* __restrict__ v,
           const unsigned short* __restrict__ wkpk, const unsigned short* __restrict__ wvpk,
           const unsigned short* __restrict__ wksumb,
           const float* __restrict__ bk, const float* __restrict__ bv,
           float* __restrict__ kv1, float* __restrict__ tG)
{
    const int ch = blockIdx.x, h = blockIdx.y, b = blockIdx.z;
    const int t = threadIdx.x, w = t >> 6, l = t & 63, g = l >> 4, m16 = l & 15;

    // weight fragments (B-operand), loaded once
    bhalf8 wkB[4][2], wvB[4][2], wks[2];
#pragma unroll
    for (int nt = 0; nt < 4; ++nt)
#pragma unroll
      for (int ks = 0; ks < 2; ++ks) {
          wkB[nt][ks] = *reinterpret_cast<const bhalf8*>(
              wkpk + ((size_t)((h * 4 + nt) * 2 + ks)) * 512 + l * 8);
          wvB[nt][ks] = *reinterpret_cast<const bhalf8*>(
              wvpk + ((size_t)((h * 4 + nt) * 2 + ks)) * 512 + l * 8);
      }
#pragma unroll
    for (int ks = 0; ks < 2; ++ks)
        wks[ks] = *reinterpret_cast<const bhalf8*>(wksumb + h * 64 + 32 * ks + 8 * g);

    float bksum;
    {
        float bl = bk[h * 64 + l];
#pragma unroll
        for (int m = 1; m < 64; m <<= 1) bl += __shfl_xor(bl, m, 64);
        bksum = bl;
    }
    float bkv[4], bvv[4];
#pragma unroll
    for (int nt = 0; nt < 4; ++nt) {
        bkv[nt] = bk[h * 64 + 16 * nt + m16];
        bvv[nt] = bv[h * 64 + 16 * nt + m16];
    }

    f32x4 kv[4][4];
#pragma unroll
    for (int i = 0; i < 4; ++i)
#pragma unroll
      for (int j = 0; j < 4; ++j) kv[i][j] = f32x4{0.f, 0.f, 0.f, 0.f};
    float tl[4] = {0.f, 0.f, 0.f, 0.f};

    const float* vw = v + ((size_t)b * NPIX + ch * 1024 + w * 256) * 64;

    for (int s = 0; s < 8; ++s) {
        // ---- A-fragments of v (bf16) straight from global f32 ----
        B8 vA[2][2];
#pragma unroll
        for (int mt = 0; mt < 2; ++mt)
#pragma unroll
          for (int ks = 0; ks < 2; ++ks) {
              const float* src = vw + (size_t)(s * 32 + 16 * mt + m16) * 64 + 32 * ks + 8 * g;
              const float4 a = *reinterpret_cast<const float4*>(src);
              const float4 c = *reinterpret_cast<const float4*>(src + 4);
              vA[mt][ks].u[0] = pk2(a.x, a.y); vA[mt][ks].u[1] = pk2(a.z, a.w);
              vA[mt][ks].u[2] = pk2(c.x, c.y); vA[mt][ks].u[3] = pk2(c.z, c.w);
          }

        // ---- K projection (C-layout: px=16mt+4g+q, d=16nt+m16) ----
        f32x4 kq[2][4];
#pragma unroll
        for (int mt = 0; mt < 2; ++mt)
#pragma unroll
          for (int nt = 0; nt < 4; ++nt) {
              f32x4 a = {0.f, 0.f, 0.f, 0.f};
              a = MFMA_BF16(vA[mt][0].v, wkB[nt][0], a, 0, 0, 0);
              a = MFMA_BF16(vA[mt][1].v, wkB[nt][1], a, 0, 0, 0);
#pragma unroll
              for (int q = 0; q < 4; ++q) a[q] += bkv[nt];
              kq[mt][nt] = a;
          }
        // ---- s1 via row-sum trick (B = wksum replicated) ----
        f32x4 st[2];
#pragma unroll
        for (int mt = 0; mt < 2; ++mt) {
            f32x4 a = {0.f, 0.f, 0.f, 0.f};
            a = MFMA_BF16(vA[mt][0].v, wks[0], a, 0, 0, 0);
            a = MFMA_BF16(vA[mt][1].v, wks[1], a, 0, 0, 0);
            st[mt] = a;
        }
        // ---- s2 per-lane partial + m16-group reduce ----
        f32x4 s2p[2];
#pragma unroll
        for (int mt = 0; mt < 2; ++mt) {
#pragma unroll
            for (int q = 0; q < 4; ++q) {
                float acc = kq[mt][0][q] * kq[mt][0][q];
                acc = fmaf(kq[mt][1][q], kq[mt][1][q], acc);
                acc = fmaf(kq[mt][2][q], kq[mt][2][q], acc);
                acc = fmaf(kq[mt][3][q], kq[mt][3][q], acc);
                s2p[mt][q] = acc;
            }
        }
#pragma unroll
        for (int mt = 0; mt < 2; ++mt)
#pragma unroll
          for (int q = 0; q < 4; ++q) {
              float x = s2p[mt][q];
              x += __shfl_xor(x, 1, 64);
              x += __shfl_xor(x, 2, 64);
              x += __shfl_xor(x, 4, 64);
              x += __shfl_xor(x, 8, 64);
              s2p[mt][q] = x;
          }
        f32x4 rsv[2], cmu[2];
#pragma unroll
        for (int mt = 0; mt < 2; ++mt)
#pragma unroll
          for (int q = 0; q < 4; ++q) {
              const float mu  = (st[mt][q] + bksum) * INV64;
              const float var = s2p[mt][q] * INV64 - mu * mu;
              const float rs  = rsqrtf(fmaxf(var, 0.f) + EPSV);
              rsv[mt][q] = rs;
              cmu[mt][q] = mu * rs;
          }
        // ---- pack K~ = rs*K into kv A-fragments (own registers!) ----
        B8 ka[4];
#pragma unroll
        for (int MT = 0; MT < 4; ++MT) {
            ka[MT].u[0] = pk2(kq[0][MT][0] * rsv[0][0], kq[0][MT][1] * rsv[0][1]);
            ka[MT].u[1] = pk2(kq[0][MT][2] * rsv[0][2], kq[0][MT][3] * rsv[0][3]);
            ka[MT].u[2] = pk2(kq[1][MT][0] * rsv[1][0], kq[1][MT][1] * rsv[1][1]);
            ka[MT].u[3] = pk2(kq[1][MT][2] * rsv[1][2], kq[1][MT][3] * rsv[1][3]);
        }
        // ---- V projection + bias ----
        f32x4 vq[2][4];
#pragma unroll
        for (int mt = 0; mt < 2; ++mt)
#pragma unroll
          for (int nt = 0; nt < 4; ++nt) {
              f32x4 a = {0.f, 0.f, 0.f, 0.f};
              a = MFMA_BF16(vA[mt][0].v, wvB[nt][0], a, 0, 0, 0);
              a = MFMA_BF16(vA[mt][1].v, wvB[nt][1], a, 0, 0, 0);
#pragma unroll
              for (int q = 0; q < 4; ++q) a[q] += bvv[nt];
              vq[mt][nt] = a;
          }
        // ---- t[e] += sum_px (mu*rs)[px] * V'[px][e] ----
#pragma unroll
        for (int nt = 0; nt < 4; ++nt) {
            float acc = tl[nt];
#pragma unroll
            for (int mt = 0; mt < 2; ++mt)
#pragma unroll
              for (int q = 0; q < 4; ++q)
                  acc = fmaf(cmu[mt][q], vq[mt][nt][q], acc);
            tl[nt] = acc;
        }
        // ---- pack V' into kv B-fragments (own registers) ----
        B8 vb[4];
#pragma unroll
        for (int NT = 0; NT < 4; ++NT) {
            vb[NT].u[0] = pk2(vq[0][NT][0], vq[0][NT][1]);
            vb[NT].u[1] = pk2(vq[0][NT][2], vq[0][NT][3]);
            vb[NT].u[2] = pk2(vq[1][NT][0], vq[1][NT][1]);
            vb[NT].u[3] = pk2(vq[1][NT][2], vq[1][NT][3]);
        }
        // ---- kv += K~^T V' ----
#pragma unroll
        for (int MT = 0; MT < 4; ++MT)
#pragma unroll
          for (int NT = 0; NT < 4; ++NT)
              kv[MT][NT] = MFMA_BF16(ka[MT].v, vb[NT].v, kv[MT][NT], 0, 0, 0);
    }

    // ---- t reduce over g-lanes, atomics ----
#pragma unroll
    for (int nt = 0; nt < 4; ++nt) {
        float x = tl[nt];
        x += __shfl_xor(x, 16, 64);
        x += __shfl_xor(x, 32, 64);
        tl[nt] = x;
    }
    if (g == 0) {
        float* td = tG + ((size_t)(b * 8 + h)) * 64;
#pragma unroll
        for (int nt = 0; nt < 4; ++nt) atomicAdd(td + 16 * nt + m16, tl[nt]);
    }

    // ---- block reduce kv across 4 waves, then coalesced atomics ----
    __shared__ float kvred[4][4096];
    __syncthreads();
#pragma unroll
    for (int MT = 0; MT < 4; ++MT)
#pragma unroll
      for (int NT = 0; NT < 4; ++NT)
#pragma unroll
        for (int q = 0; q < 4; ++q)
            kvred[w][(16 * MT + 4 * g + q) * 64 + 16 * NT + m16] = kv[MT][NT][q];
    __syncthreads();
    float* dstg = kv1 + ((size_t)(b * 8 + h)) * 4096;
#pragma unroll
    for (int i = 0; i < 16; ++i) {
        const int idx = i * 256 + t;
        atomicAdd(dstg + idx,
                  kvred[0][idx] + kvred[1][idx] + kvred[2][idx] + kvred[3][idx]);
    }
}

// ---------------------------------------------------------------------------
// k2: per (h,b): kvF = gk*(kv1 - 1 (x) t) + bk (x) Sv ; M = kvF @ Wo_h ;
// write M' = gq*M/n as frag-packed bf16 (k3's permuted B layout);
// cbeta += (bq^T M)/n (+ Wo_b/n once).
// ---------------------------------------------------------------------------
__global__ void k2_mix(const float* __restrict__ kv1,  const float* __restrict__ tG,
                       const float* __restrict__ vsum,
                       const float* __restrict__ Wv,   const float* __restrict__ bv,
                       const float* __restrict__ lnkg, const float* __restrict__ lnkb,
                       const float* __restrict__ lnqg, const float* __restrict__ lnqb,
                       const float* __restrict__ Wo,   const float* __restrict__ Wob,
                       unsigned short* __restrict__ mpk, float* __restrict__ cbeta)
{
    const int h = blockIdx.x, b = blockIdx.y, t = threadIdx.x;
    __shared__ float kvs[64][65], wos[64][65], mls[64][65], Svs[64], us[64];
    const int r = t >> 2, c0 = (t & 3) * 16;
    const float* kg = kv1 + ((size_t)(b * 8 + h)) * 4096;
    const float* td = tG + ((size_t)(b * 8 + h)) * 64;
#pragma unroll
    for (int i = 0; i < 16; i += 4) {
        const float4 x = *reinterpret_cast<const float4*>(kg + r * 64 + c0 + i);
        kvs[r][c0+i] = x.x; kvs[r][c0+i+1] = x.y; kvs[r][c0+i+2] = x.z; kvs[r][c0+i+3] = x.w;
    }
#pragma unroll
    for (int i = 0; i < 16; i += 4) {
        const float4 x = *reinterpret_cast<const float4*>(Wo + ((size_t)(h * 64) + r) * 64 + c0 + i);
        wos[r][c0+i] = x.x; wos[r][c0+i+1] = x.y; wos[r][c0+i+2] = x.z; wos[r][c0+i+3] = x.w;
    }
    if (t < 64) {
        float s = 16384.f * bv[h * 64 + t];
        for (int cc = 0; cc < 64; ++cc)
            s = fmaf(vsum[b * 64 + cc], Wv[cc * 512 + h * 64 + t], s);
        Svs[t] = s;
    }
    __syncthreads();
    {
        const float gk = lnkg[h * 64 + r], bk2 = lnkb[h * 64 + r];
#pragma unroll
        for (int i = 0; i < 16; ++i) {
            const int e = c0 + i;
            kvs[r][e] = gk * (kvs[r][e] - td[e]) + bk2 * Svs[e];
        }
    }
    __syncthreads();
    if (t < 64) {
        float s = 0.f;
        for (int dd = 0; dd < 64; ++dd) s = fmaf(lnqb[h * 64 + dd], kvs[dd][t], s);
        us[t] = s;
    }
    float mrow[16];
#pragma unroll
    for (int i = 0; i < 16; ++i) mrow[i] = 0.f;
    for (int e2 = 0; e2 < 64; ++e2) {
        const float kr = kvs[r][e2];
#pragma unroll
        for (int i = 0; i < 16; ++i) mrow[i] = fmaf(kr, wos[e2][c0 + i], mrow[i]);
    }
    {
        const float gq = lnqg[h * 64 + r] * INV_N;
#pragma unroll
        for (int i = 0; i < 16; ++i) mls[r][c0 + i] = gq * mrow[i];
    }
    __syncthreads();
    if (t < 64) {
        float s = 0.f;
        for (int e2 = 0; e2 < 64; ++e2) s = fmaf(us[e2], wos[e2][t], s);
        atomicAdd(cbeta + b * 64 + t, s * INV_N);
        if (h == 0) atomicAdd(cbeta + b * 64 + t, Wob[t] * INV_N);
    }
    // frag-packed M' with permuted k-slot map d = 32ks+16(j>>2)+4g+(j&3)
#pragma unroll
    for (int i = 0; i < 2; ++i) {
        const int f = t * 2 + i;
        const int nt = (f >> 7) & 3, ks = (f >> 6) & 1, l = f & 63;
        const int g = l >> 4, m = l & 15;
        unsigned short o[8];
#pragma unroll
        for (int j = 0; j < 8; ++j) {
            const int d = 32 * ks + 16 * (j >> 2) + 4 * g + (j & 3);
            o[j] = f2bf(mls[d][16 * nt + m]);
        }
        unsigned short* dd = mpk + ((size_t)((b * 8 + h) * 8 + nt * 2 + ks)) * 512 + l * 8;
        *reinterpret_cast<ushort4*>(dd)     = make_ushort4(o[0], o[1], o[2], o[3]);
        *reinterpret_cast<ushort4*>(dd + 4) = make_ushort4(o[4], o[5], o[6], o[7]);
    }
}

// ---------------------------------------------------------------------------
// k3: wave = 32 px. Per head: transposed Q proj (C [d][px]), 2-shfl LN,
// normalized fragments are OWN registers (permuted slot map), out += Q~.M'.
// Coalesced [px][e] epilogue. No LDS at all.
// ---------------------------------------------------------------------------
__global__ __launch_bounds__(256, 2)
void k3_out(const float* __restrict__ v,
            const unsigned short* __restrict__ wqpk, const float* __restrict__ bq,
            const unsigned short* __restrict__ mpk,  const float* __restrict__ cbeta,
            float* __restrict__ out)
{
    const int blk = blockIdx.x, b = blockIdx.y;
    const int t = threadIdx.x, w = t >> 6, l = t & 63, g = l >> 4, m16 = l & 15;
    const size_t px0 = (size_t)b * NPIX + blk * 128 + w * 32;

    // v B-fragments (B[k=c][n=px]) straight from global f32
    B8 vB[2][2];
#pragma unroll
    for (int nt = 0; nt < 2; ++nt)
#pragma unroll
      for (int ks = 0; ks < 2; ++ks) {
          const float* src = v + (px0 + 16 * nt + m16) * 64 + 32 * ks + 8 * g;
          const float4 a = *reinterpret_cast<const float4*>(src);
          const float4 c = *reinterpret_cast<const float4*>(src + 4);
          vB[nt][ks].u[0] = pk2(a.x, a.y); vB[nt][ks].u[1] = pk2(a.z, a.w);
          vB[nt][ks].u[2] = pk2(c.x, c.y); vB[nt][ks].u[3] = pk2(c.z, c.w);
      }
    float cbv[4];
#pragma unroll
    for (int nt = 0; nt < 4; ++nt) cbv[nt] = cbeta[b * 64 + 16 * nt + m16];

    f32x4 outa[2][4];
#pragma unroll
    for (int i = 0; i < 2; ++i)
#pragma unroll
      for (int j = 0; j < 4; ++j) outa[i][j] = f32x4{0.f, 0.f, 0.f, 0.f};

    for (int h = 0; h < 8; ++h) {
        bhalf8 wqA[4][2], mB[2][4];
#pragma unroll
        for (int mt = 0; mt < 4; ++mt)
#pragma unroll
          for (int ks = 0; ks < 2; ++ks)
            wqA[mt][ks] = *reinterpret_cast<const bhalf8*>(
                wqpk + ((size_t)((h * 4 + mt) * 2 + ks)) * 512 + l * 8);
#pragma unroll
        for (int ks = 0; ks < 2; ++ks)
#pragma unroll
          for (int nt = 0; nt < 4; ++nt)
            mB[ks][nt] = *reinterpret_cast<const bhalf8*>(
                mpk + ((size_t)((b * 8 + h) * 8 + nt * 2 + ks)) * 512 + l * 8);
        float4 bq4[4];
#pragma unroll
        for (int mt = 0; mt < 4; ++mt)
            bq4[mt] = *reinterpret_cast<const float4*>(bq + h * 64 + 16 * mt + 4 * g);

        // Q^T projection (C-layout: d=16mt+4g+q, px=16nt+m16) + bias
        f32x4 qa[4][2];
#pragma unroll
        for (int mt = 0; mt < 4; ++mt)
#pragma unroll
          for (int nt = 0; nt < 2; ++nt) {
              f32x4 a = {0.f, 0.f, 0.f, 0.f};
              a = MFMA_BF16(wqA[mt][0], vB[nt][0].v, a, 0, 0, 0);
              a = MFMA_BF16(wqA[mt][1], vB[nt][1].v, a, 0, 0, 0);
              a[0] += bq4[mt].x; a[1] += bq4[mt].y;
              a[2] += bq4[mt].z; a[3] += bq4[mt].w;
              qa[mt][nt] = a;
          }
        // LN over d (2 shfls per stat per px-tile)
        float mu[2], rs[2];
#pragma unroll
        for (int nt = 0; nt < 2; ++nt) {
            float s1 = 0.f, s2 = 0.f;
#pragma unroll
            for (int mt = 0; mt < 4; ++mt)
#pragma unroll
              for (int q = 0; q < 4; ++q) {
                  const float x = qa[mt][nt][q];
                  s1 += x; s2 = fmaf(x, x, s2);
              }
            s1 += __shfl_xor(s1, 16, 64); s1 += __shfl_xor(s1, 32, 64);
            s2 += __shfl_xor(s2, 16, 64); s2 += __shfl_xor(s2, 32, 64);
            mu[nt] = s1 * INV64;
            rs[nt] = rsqrtf(fmaxf(s2 * INV64 - mu[nt] * mu[nt], 0.f) + EPSV);
        }
        // pack normalized Q fragments (own registers, permuted slot map)
        B8 ka[2][2];
#pragma unroll
        for (int MT = 0; MT < 2; ++MT)
#pragma unroll
          for (int ks = 0; ks < 2; ++ks) {
              ka[MT][ks].u[0] = pk2((qa[2*ks+0][MT][0] - mu[MT]) * rs[MT],
                                    (qa[2*ks+0][MT][1] - mu[MT]) * rs[MT]);
              ka[MT][ks].u[1] = pk2((qa[2*ks+0][MT][2] - mu[MT]) * rs[MT],
                                    (qa[2*ks+0][MT][3] - mu[MT]) * rs[MT]);
              ka[MT][ks].u[2] = pk2((qa[2*ks+1][MT][0] - mu[MT]) * rs[MT],
                                    (qa[2*ks+1][MT][1] - mu[MT]) * rs[MT]);
              ka[MT][ks].u[3] = pk2((qa[2*ks+1][MT][2] - mu[MT]) * rs[MT],
                                    (qa[2*ks+1][MT][3] - mu[MT]) * rs[MT]);
          }
        // out += Q~ . M'
#pragma unroll
        for (int MT = 0; MT < 2; ++MT)
#pragma unroll
          for (int nt = 0; nt < 4; ++nt) {
              outa[MT][nt] = MFMA_BF16(ka[MT][0].v, mB[0][nt], outa[MT][nt], 0, 0, 0);
              outa[MT][nt] = MFMA_BF16(ka[MT][1].v, mB[1][nt], outa[MT][nt], 0, 0, 0);
          }
    }

    // epilogue: out[px][e] = outa + cbeta  (line-coalesced scalar stores)
#pragma unroll
    for (int MT = 0; MT < 2; ++MT)
#pragma unroll
      for (int q = 0; q < 4; ++q) {
          float* orow = out + (px0 + 16 * MT + 4 * g + q) * 64;
#pragma unroll
          for (int nt = 0; nt < 4; ++nt)
              orow[16 * nt + m16] = outa[MT][nt][q] + cbv[nt];
      }
}

} // namespace

extern "C" void kernel_launch(void* const* d_in, const int* in_sizes, int n_in,
                              void* d_out, int out_size, void* d_ws, size_t ws_size,
                              hipStream_t stream)
{
    const float* v     = (const float*)d_in[0];
    const float* Wq_w  = (const float*)d_in[1];
    const float* Wq_b  = (const float*)d_in[2];
    const float* Wk_w  = (const float*)d_in[3];
    const float* Wk_b  = (const float*)d_in[4];
    const float* Wv_w  = (const float*)d_in[5];
    const float* Wv_b  = (const float*)d_in[6];
    const float* lnq_g = (const float*)d_in[7];
    const float* lnq_b = (const float*)d_in[8];
    const float* lnk_g = (const float*)d_in[9];
    const float* lnk_b = (const float*)d_in[10];
    const float* Wo_w  = (const float*)d_in[11];
    const float* Wo_b  = (const float*)d_in[12];
    float* out = (float*)d_out;

    float* wsf   = (float*)d_ws;
    float* kv1   = wsf + KV1_OFF;
    float* tG    = wsf + T_OFF;
    float* vsum  = wsf + VSUM_OFF;
    float* cbeta = wsf + CBETA_OFF;
    unsigned short* base_s = (unsigned short*)(wsf + FZERO_CNT);
    unsigned short* wkpk   = base_s;
    unsigned short* wvpk   = base_s + 32768;
    unsigned short* wqpk   = base_s + 65536;
    unsigned short* wksumb = base_s + 98304;
    unsigned short* mpk    = base_s + 98816;

    hipMemsetAsync(d_ws, 0, (size_t)FZERO_CNT * sizeof(float), stream);
    k0_vsum<<<dim3(128, 4), 256, 0, stream>>>(v, vsum);
    kpack<<<24, 256, 0, stream>>>(Wk_w, Wv_w, Wq_w, wkpk, wvpk, wqpk, wksumb);
    k1_kv<<<dim3(16, 8, 4), 256, 0, stream>>>(v, wkpk, wvpk, wksumb, Wk_b, Wv_b,
                                              kv1, tG);
    k2_mix<<<dim3(8, 4), 256, 0, stream>>>(kv1, tG, vsum, Wv_w, Wv_b,
                                           lnk_g, lnk_b, lnq_g, lnq_b,
                                           Wo_w, Wo_b, mpk, cbeta);
    k3_out<<<dim3(128, 4), 256, 0, stream>>>(v, wqpk, Wq_b, mpk, cbeta, out);
}

// Round 4
// 161.301 us; speedup vs baseline: 17.1446x; 1.1089x over previous
//
#include <hip/hip_runtime.h>
#include <hip/hip_bf16.h>

typedef __attribute__((ext_vector_type(8))) short bhalf8;
typedef __attribute__((ext_vector_type(4))) float f32x4;

#define MFMA_BF16 __builtin_amdgcn_mfma_f32_16x16x32_bf16

namespace {

constexpr int   NPIX  = 16384;
constexpr int   NCH   = 64;          // 256-px chunks per batch
constexpr int   TILE  = 66 * 64;     // partial tile: 64 kv rows + t row + Sv row
constexpr float EPSV  = 1e-5f;
constexpr float INV64 = 1.0f / 64.0f;
constexpr float INV_N = 1.0f / 16384.0f;

__device__ __forceinline__ unsigned short f2bf(float f) {
    unsigned int u = __builtin_bit_cast(unsigned int, f);
    u += 0x7fffu + ((u >> 16) & 1u);
    return (unsigned short)(u >> 16);
}

union B8 { bhalf8 v; unsigned int u[4]; };

__device__ __forceinline__ unsigned int pk2(float a, float b) {
    union { __hip_bfloat162 h; unsigned int u; } x;
    x.h = __float22bfloat162_rn(float2{a, b});
    return x.u;
}

// ---------------------------------------------------------------------------
// kpack: pre-pack weight fragments (bf16); wksum rows for the s1 trick;
// zero cbeta (replaces the memset kernel).
// ---------------------------------------------------------------------------
__global__ void kpack(const float* __restrict__ Wk, const float* __restrict__ Wv,
                      const float* __restrict__ Wq,
                      unsigned short* __restrict__ wkpk, unsigned short* __restrict__ wvpk,
                      unsigned short* __restrict__ wqpk, unsigned short* __restrict__ wksumb,
                      float* __restrict__ cbeta)
{
    const int w = blockIdx.x >> 3, h = blockIdx.x & 7, t = threadIdx.x;
    const float* W = (w == 0) ? Wk : (w == 1) ? Wv : Wq;
    unsigned short* dst = (w == 0) ? wkpk : (w == 1) ? wvpk : wqpk;

    if (blockIdx.x == 0) cbeta[t] = 0.f;   // 256 floats

#pragma unroll
    for (int i = 0; i < 2; ++i) {
        const int f = t * 2 + i;
        const int nt = (f >> 7) & 3, ks = (f >> 6) & 1, l = f & 63;
        const int g = l >> 4, m = l & 15;
        unsigned short tmp[8];
#pragma unroll
        for (int j = 0; j < 8; ++j)
            tmp[j] = f2bf(W[(size_t)(32 * ks + 8 * g + j) * 512 + h * 64 + 16 * nt + m]);
        unsigned short* d = dst + ((size_t)((h * 4 + nt) * 2 + ks)) * 512 + l * 8;
        *reinterpret_cast<ushort4*>(d)     = make_ushort4(tmp[0], tmp[1], tmp[2], tmp[3]);
        *reinterpret_cast<ushort4*>(d + 4) = make_ushort4(tmp[4], tmp[5], tmp[6], tmp[7]);
    }
    if (w == 0 && t < 64) {
        float s = 0.f;
        const float* row = Wk + (size_t)t * 512 + h * 64;
#pragma unroll
        for (int d = 0; d < 64; ++d) s += row[d];
        wksumb[h * 64 + t] = f2bf(s);
    }
}

// ---------------------------------------------------------------------------
// KA: block = (chunk of 256 px, b), 8 waves. Stage v once to LDS in fragment
// order; wave w = head w does K/V projection, LN-fold, kv accumulation fully
// in registers (permuted k-slot map -> zero cross-lane traffic), then writes
// a per-chunk partial tile [66][64]: rows 0-63 kv, row 64 t, row 65 Sv.
// ---------------------------------------------------------------------------
__global__ __launch_bounds__(512, 2)
void ka_kv(const float* __restrict__ v,
           const unsigned short* __restrict__ wkpk, const unsigned short* __restrict__ wvpk,
           const unsigned short* __restrict__ wksumb,
           const float* __restrict__ bk, const float* __restrict__ bv,
           float* __restrict__ part)
{
    const int ch = blockIdx.x, b = blockIdx.y;
    const int t = threadIdx.x, h = t >> 6, l = t & 63, g = l >> 4, m16 = l & 15;

    __shared__ uint4 vlds4[2048];                       // 32 KB, fragment-ordered
    unsigned short* vlds = reinterpret_cast<unsigned short*>(vlds4);

    // ---- stage 256 px x 64 c (fragment order: [s][mt*2+ks][lane][8]) ----
    const float* vbase = v + ((size_t)b * NPIX + ch * 256) * 64;
#pragma unroll
    for (int i = 0; i < 4; ++i) {
        const int G = t + 512 * i;
        const int s = G >> 8, f = (G >> 6) & 3, ll = G & 63;
        const int mt = f >> 1, ks = f & 1, gg = ll >> 4, mm = ll & 15;
        const float* src = vbase + (size_t)(s * 32 + 16 * mt + mm) * 64 + 32 * ks + 8 * gg;
        const float4 a = *reinterpret_cast<const float4*>(src);
        const float4 c = *reinterpret_cast<const float4*>(src + 4);
        vlds4[G] = uint4{pk2(a.x, a.y), pk2(a.z, a.w), pk2(c.x, c.y), pk2(c.z, c.w)};
    }

    // ---- per-wave head state ----
    bhalf8 wkB[4][2], wvB[4][2], wks[2];
#pragma unroll
    for (int nt = 0; nt < 4; ++nt)
#pragma unroll
      for (int ks = 0; ks < 2; ++ks) {
          wkB[nt][ks] = *reinterpret_cast<const bhalf8*>(
              wkpk + ((size_t)((h * 4 + nt) * 2 + ks)) * 512 + l * 8);
          wvB[nt][ks] = *reinterpret_cast<const bhalf8*>(
              wvpk + ((size_t)((h * 4 + nt) * 2 + ks)) * 512 + l * 8);
      }
#pragma unroll
    for (int ks = 0; ks < 2; ++ks)
        wks[ks] = *reinterpret_cast<const bhalf8*>(wksumb + h * 64 + 32 * ks + 8 * g);

    float bksum;
    {
        float bl = bk[h * 64 + l];
#pragma unroll
        for (int m = 1; m < 64; m <<= 1) bl += __shfl_xor(bl, m, 64);
        bksum = bl;
    }
    float bkv[4], bvv[4];
#pragma unroll
    for (int nt = 0; nt < 4; ++nt) {
        bkv[nt] = bk[h * 64 + 16 * nt + m16];
        bvv[nt] = bv[h * 64 + 16 * nt + m16];
    }

    f32x4 kv[4][4];
#pragma unroll
    for (int i = 0; i < 4; ++i)
#pragma unroll
      for (int j = 0; j < 4; ++j) kv[i][j] = f32x4{0.f, 0.f, 0.f, 0.f};
    float tl[4] = {0.f, 0.f, 0.f, 0.f};
    float sv[4] = {0.f, 0.f, 0.f, 0.f};

    __syncthreads();

    for (int s = 0; s < 8; ++s) {
        // ---- v A-fragments from LDS (conflict-free b128) ----
        bhalf8 vA[2][2];
#pragma unroll
        for (int mt = 0; mt < 2; ++mt)
#pragma unroll
          for (int ks = 0; ks < 2; ++ks)
            vA[mt][ks] = *reinterpret_cast<const bhalf8*>(
                vlds + ((size_t)(s * 4 + mt * 2 + ks) * 64 + l) * 8);

        // ---- K projection (C: px=16mt+4g+q, d=16nt+m16) + bias ----
        f32x4 kq[2][4];
#pragma unroll
        for (int mt = 0; mt < 2; ++mt)
#pragma unroll
          for (int nt = 0; nt < 4; ++nt) {
              f32x4 a = {0.f, 0.f, 0.f, 0.f};
              a = MFMA_BF16(vA[mt][0], wkB[nt][0], a, 0, 0, 0);
              a = MFMA_BF16(vA[mt][1], wkB[nt][1], a, 0, 0, 0);
#pragma unroll
              for (int q = 0; q < 4; ++q) a[q] += bkv[nt];
              kq[mt][nt] = a;
          }
        // ---- s1 via row-sum MFMA trick ----
        f32x4 st[2];
#pragma unroll
        for (int mt = 0; mt < 2; ++mt) {
            f32x4 a = {0.f, 0.f, 0.f, 0.f};
            a = MFMA_BF16(vA[mt][0], wks[0], a, 0, 0, 0);
            a = MFMA_BF16(vA[mt][1], wks[1], a, 0, 0, 0);
            st[mt] = a;
        }
        // ---- s2 partial + m16-group reduce ----
        f32x4 s2p[2];
#pragma unroll
        for (int mt = 0; mt < 2; ++mt)
#pragma unroll
          for (int q = 0; q < 4; ++q) {
              float acc = kq[mt][0][q] * kq[mt][0][q];
              acc = fmaf(kq[mt][1][q], kq[mt][1][q], acc);
              acc = fmaf(kq[mt][2][q], kq[mt][2][q], acc);
              acc = fmaf(kq[mt][3][q], kq[mt][3][q], acc);
              s2p[mt][q] = acc;
          }
#pragma unroll
        for (int mt = 0; mt < 2; ++mt)
#pragma unroll
          for (int q = 0; q < 4; ++q) {
              float x = s2p[mt][q];
              x += __shfl_xor(x, 1, 64);
              x += __shfl_xor(x, 2, 64);
              x += __shfl_xor(x, 4, 64);
              x += __shfl_xor(x, 8, 64);
              s2p[mt][q] = x;
          }
        f32x4 rsv[2], cmu[2];
#pragma unroll
        for (int mt = 0; mt < 2; ++mt)
#pragma unroll
          for (int q = 0; q < 4; ++q) {
              const float mu  = (st[mt][q] + bksum) * INV64;
              const float var = s2p[mt][q] * INV64 - mu * mu;
              const float rs  = rsqrtf(fmaxf(var, 0.f) + EPSV);
              rsv[mt][q] = rs;
              cmu[mt][q] = mu * rs;
          }
        // ---- pack K~ = rs*K into kv A-fragments (own registers) ----
        B8 ka[4];
#pragma unroll
        for (int MT = 0; MT < 4; ++MT) {
            ka[MT].u[0] = pk2(kq[0][MT][0] * rsv[0][0], kq[0][MT][1] * rsv[0][1]);
            ka[MT].u[1] = pk2(kq[0][MT][2] * rsv[0][2], kq[0][MT][3] * rsv[0][3]);
            ka[MT].u[2] = pk2(kq[1][MT][0] * rsv[1][0], kq[1][MT][1] * rsv[1][1]);
            ka[MT].u[3] = pk2(kq[1][MT][2] * rsv[1][2], kq[1][MT][3] * rsv[1][3]);
        }
        // ---- V projection + bias ----
        f32x4 vq[2][4];
#pragma unroll
        for (int mt = 0; mt < 2; ++mt)
#pragma unroll
          for (int nt = 0; nt < 4; ++nt) {
              f32x4 a = {0.f, 0.f, 0.f, 0.f};
              a = MFMA_BF16(vA[mt][0], wvB[nt][0], a, 0, 0, 0);
              a = MFMA_BF16(vA[mt][1], wvB[nt][1], a, 0, 0, 0);
#pragma unroll
              for (int q = 0; q < 4; ++q) a[q] += bvv[nt];
              vq[mt][nt] = a;
          }
        // ---- t[e] += mu*rs . V'; Sv[e] += V' ----
#pragma unroll
        for (int nt = 0; nt < 4; ++nt) {
            float acc = tl[nt], acc2 = sv[nt];
#pragma unroll
            for (int mt = 0; mt < 2; ++mt)
#pragma unroll
              for (int q = 0; q < 4; ++q) {
                  acc  = fmaf(cmu[mt][q], vq[mt][nt][q], acc);
                  acc2 += vq[mt][nt][q];
              }
            tl[nt] = acc; sv[nt] = acc2;
        }
        // ---- pack V' into kv B-fragments (own registers) ----
        B8 vb[4];
#pragma unroll
        for (int NT = 0; NT < 4; ++NT) {
            vb[NT].u[0] = pk2(vq[0][NT][0], vq[0][NT][1]);
            vb[NT].u[1] = pk2(vq[0][NT][2], vq[0][NT][3]);
            vb[NT].u[2] = pk2(vq[1][NT][0], vq[1][NT][1]);
            vb[NT].u[3] = pk2(vq[1][NT][2], vq[1][NT][3]);
        }
        // ---- kv += K~^T V' ----
#pragma unroll
        for (int MT = 0; MT < 4; ++MT)
#pragma unroll
          for (int NT = 0; NT < 4; ++NT)
              kv[MT][NT] = MFMA_BF16(ka[MT].v, vb[NT].v, kv[MT][NT], 0, 0, 0);
    }

    // ---- reduce t/Sv over g lanes; write partial tile ----
#pragma unroll
    for (int nt = 0; nt < 4; ++nt) {
        float x = tl[nt];
        x += __shfl_xor(x, 16, 64); x += __shfl_xor(x, 32, 64);
        tl[nt] = x;
        float y = sv[nt];
        y += __shfl_xor(y, 16, 64); y += __shfl_xor(y, 32, 64);
        sv[nt] = y;
    }
    float* pdst = part + ((size_t)((b * NCH + ch) * 8 + h)) * TILE;
#pragma unroll
    for (int MT = 0; MT < 4; ++MT)
#pragma unroll
      for (int NT = 0; NT < 4; ++NT)
#pragma unroll
        for (int q = 0; q < 4; ++q)
            pdst[(16 * MT + 4 * g + q) * 64 + 16 * NT + m16] = kv[MT][NT][q];
    if (g == 0) {
#pragma unroll
        for (int nt = 0; nt < 4; ++nt) {
            pdst[64 * 64 + 16 * nt + m16] = tl[nt];
            pdst[65 * 64 + 16 * nt + m16] = sv[nt];
        }
    }
}

// ---------------------------------------------------------------------------
// k2a: parallel partial reduce: 8 chunks -> 1 tile. Grid (seg=8, bh=32).
// ---------------------------------------------------------------------------
__global__ void k2a_reduce(const float* __restrict__ part, float* __restrict__ s2buf)
{
    const int seg = blockIdx.x, bh = blockIdx.y, t = threadIdx.x;
    const int b = bh >> 3, hh = bh & 7;
    const float* base = part + ((size_t)((b * NCH + seg * 8) * 8 + hh)) * TILE;
    float* dst = s2buf + ((size_t)(bh * 8 + seg)) * TILE;
#pragma unroll
    for (int k = 0; k < 5; ++k) {
        const int idx = t + k * 256;              // float4 index, 1056 total
        if (idx < TILE / 4) {
            float4 s = make_float4(0.f, 0.f, 0.f, 0.f);
#pragma unroll
            for (int i = 0; i < 8; ++i) {
                const float4 x = *reinterpret_cast<const float4*>(
                    base + (size_t)i * 8 * TILE + idx * 4);
                s.x += x.x; s.y += x.y; s.z += x.z; s.w += x.w;
            }
            *reinterpret_cast<float4*>(dst + idx * 4) = s;
        }
    }
}

// ---------------------------------------------------------------------------
// k2b: final reduce + mix: kvF = gk*(kv - t) + bk (x) Sv; M = kvF @ Wo_h;
// mpk = frag-packed gq*M/n; cbeta += bq^T M / n (+ Wo_b/n once).
// ---------------------------------------------------------------------------
__global__ void k2b_mix(const float* __restrict__ s2buf,
                        const float* __restrict__ lnkg, const float* __restrict__ lnkb,
                        const float* __restrict__ lnqg, const float* __restrict__ lnqb,
                        const float* __restrict__ Wo,   const float* __restrict__ Wob,
                        unsigned short* __restrict__ mpk, float* __restrict__ cbeta)
{
    const int h = blockIdx.x, b = blockIdx.y, t = threadIdx.x;
    __shared__ float kvs[64][65], wos[64][65], mls[64][65], Svs[64], tds[64], us[64];
    const int r = t >> 2, c0 = (t & 3) * 16;
    const float* sb = s2buf + ((size_t)((b * 8 + h) * 8)) * TILE;

    float acc[16];
#pragma unroll
    for (int i = 0; i < 16; ++i) acc[i] = 0.f;
#pragma unroll
    for (int seg = 0; seg < 8; ++seg) {
        const float* src = sb + (size_t)seg * TILE + r * 64 + c0;
#pragma unroll
        for (int q = 0; q < 4; ++q) {
            const float4 x = *reinterpret_cast<const float4*>(src + 4 * q);
            acc[4*q+0] += x.x; acc[4*q+1] += x.y; acc[4*q+2] += x.z; acc[4*q+3] += x.w;
        }
    }
#pragma unroll
    for (int i = 0; i < 16; ++i) kvs[r][c0 + i] = acc[i];

    if (t < 64) {
        float s = 0.f, s2 = 0.f;
#pragma unroll
        for (int seg = 0; seg < 8; ++seg) {
            s  += sb[(size_t)seg * TILE + 64 * 64 + t];
            s2 += sb[(size_t)seg * TILE + 65 * 64 + t];
        }
        tds[t] = s; Svs[t] = s2;
    }
#pragma unroll
    for (int i = 0; i < 16; i += 4) {
        const float4 x = *reinterpret_cast<const float4*>(
            Wo + ((size_t)(h * 64) + r) * 64 + c0 + i);
        wos[r][c0+i] = x.x; wos[r][c0+i+1] = x.y; wos[r][c0+i+2] = x.z; wos[r][c0+i+3] = x.w;
    }
    __syncthreads();
    {
        const float gk = lnkg[h * 64 + r], bk2 = lnkb[h * 64 + r];
#pragma unroll
        for (int i = 0; i < 16; ++i) {
            const int e = c0 + i;
            kvs[r][e] = gk * (kvs[r][e] - tds[e]) + bk2 * Svs[e];
        }
    }
    __syncthreads();
    if (t < 64) {
        float s = 0.f;
        for (int dd = 0; dd < 64; ++dd) s = fmaf(lnqb[h * 64 + dd], kvs[dd][t], s);
        us[t] = s;
    }
    float mrow[16];
#pragma unroll
    for (int i = 0; i < 16; ++i) mrow[i] = 0.f;
    for (int e2 = 0; e2 < 64; ++e2) {
        const float kr = kvs[r][e2];
#pragma unroll
        for (int i = 0; i < 16; ++i) mrow[i] = fmaf(kr, wos[e2][c0 + i], mrow[i]);
    }
    {
        const float gq = lnqg[h * 64 + r] * INV_N;
#pragma unroll
        for (int i = 0; i < 16; ++i) mls[r][c0 + i] = gq * mrow[i];
    }
    __syncthreads();
    if (t < 64) {
        float s = 0.f;
        for (int e2 = 0; e2 < 64; ++e2) s = fmaf(us[e2], wos[e2][t], s);
        atomicAdd(cbeta + b * 64 + t, s * INV_N);
        if (h == 0) atomicAdd(cbeta + b * 64 + t, Wob[t] * INV_N);
    }
    // frag-packed M' with permuted k-slot map d = 32ks+16(j>>2)+4g+(j&3)
#pragma unroll
    for (int i = 0; i < 2; ++i) {
        const int f = t * 2 + i;
        const int nt = (f >> 7) & 3, ks = (f >> 6) & 1, l = f & 63;
        const int g = l >> 4, m = l & 15;
        unsigned short o[8];
#pragma unroll
        for (int j = 0; j < 8; ++j) {
            const int d = 32 * ks + 16 * (j >> 2) + 4 * g + (j & 3);
            o[j] = f2bf(mls[d][16 * nt + m]);
        }
        unsigned short* dd = mpk + ((size_t)((b * 8 + h) * 8 + nt * 2 + ks)) * 512 + l * 8;
        *reinterpret_cast<ushort4*>(dd)     = make_ushort4(o[0], o[1], o[2], o[3]);
        *reinterpret_cast<ushort4*>(dd + 4) = make_ushort4(o[4], o[5], o[6], o[7]);
    }
}

// ---------------------------------------------------------------------------
// k3: wave = 32 px; fully-unrolled head loop so all fragment loads pipeline.
// ---------------------------------------------------------------------------
__global__ __launch_bounds__(256, 2)
void k3_out(const float* __restrict__ v,
            const unsigned short* __restrict__ wqpk, const float* __restrict__ bq,
            const unsigned short* __restrict__ mpk,  const float* __restrict__ cbeta,
            float* __restrict__ out)
{
    const int blk = blockIdx.x, b = blockIdx.y;
    const int t = threadIdx.x, w = t >> 6, l = t & 63, g = l >> 4, m16 = l & 15;
    const size_t px0 = (size_t)b * NPIX + blk * 128 + w * 32;

    B8 vB[2][2];
#pragma unroll
    for (int nt = 0; nt < 2; ++nt)
#pragma unroll
      for (int ks = 0; ks < 2; ++ks) {
          const float* src = v + (px0 + 16 * nt + m16) * 64 + 32 * ks + 8 * g;
          const float4 a = *reinterpret_cast<const float4*>(src);
          const float4 c = *reinterpret_cast<const float4*>(src + 4);
          vB[nt][ks].u[0] = pk2(a.x, a.y); vB[nt][ks].u[1] = pk2(a.z, a.w);
          vB[nt][ks].u[2] = pk2(c.x, c.y); vB[nt][ks].u[3] = pk2(c.z, c.w);
      }
    float cbv[4];
#pragma unroll
    for (int nt = 0; nt < 4; ++nt) cbv[nt] = cbeta[b * 64 + 16 * nt + m16];

    f32x4 outa[2][4];
#pragma unroll
    for (int i = 0; i < 2; ++i)
#pragma unroll
      for (int j = 0; j < 4; ++j) outa[i][j] = f32x4{0.f, 0.f, 0.f, 0.f};

#pragma unroll
    for (int h = 0; h < 8; ++h) {
        bhalf8 wqA[4][2], mB[2][4];
#pragma unroll
        for (int mt = 0; mt < 4; ++mt)
#pragma unroll
          for (int ks = 0; ks < 2; ++ks)
            wqA[mt][ks] = *reinterpret_cast<const bhalf8*>(
                wqpk + ((size_t)((h * 4 + mt) * 2 + ks)) * 512 + l * 8);
#pragma unroll
        for (int ks = 0; ks < 2; ++ks)
#pragma unroll
          for (int nt = 0; nt < 4; ++nt)
            mB[ks][nt] = *reinterpret_cast<const bhalf8*>(
                mpk + ((size_t)((b * 8 + h) * 8 + nt * 2 + ks)) * 512 + l * 8);
        float4 bq4[4];
#pragma unroll
        for (int mt = 0; mt < 4; ++mt)
            bq4[mt] = *reinterpret_cast<const float4*>(bq + h * 64 + 16 * mt + 4 * g);

        f32x4 qa[4][2];
#pragma unroll
        for (int mt = 0; mt < 4; ++mt)
#pragma unroll
          for (int nt = 0; nt < 2; ++nt) {
              f32x4 a = {0.f, 0.f, 0.f, 0.f};
              a = MFMA_BF16(wqA[mt][0], vB[nt][0].v, a, 0, 0, 0);
              a = MFMA_BF16(wqA[mt][1], vB[nt][1].v, a, 0, 0, 0);
              a[0] += bq4[mt].x; a[1] += bq4[mt].y;
              a[2] += bq4[mt].z; a[3] += bq4[mt].w;
              qa[mt][nt] = a;
          }
        float mu[2], rs[2];
#pragma unroll
        for (int nt = 0; nt < 2; ++nt) {
            float s1 = 0.f, s2 = 0.f;
#pragma unroll
            for (int mt = 0; mt < 4; ++mt)
#pragma unroll
              for (int q = 0; q < 4; ++q) {
                  const float x = qa[mt][nt][q];
                  s1 += x; s2 = fmaf(x, x, s2);
              }
            s1 += __shfl_xor(s1, 16, 64); s1 += __shfl_xor(s1, 32, 64);
            s2 += __shfl_xor(s2, 16, 64); s2 += __shfl_xor(s2, 32, 64);
            mu[nt] = s1 * INV64;
            rs[nt] = rsqrtf(fmaxf(s2 * INV64 - mu[nt] * mu[nt], 0.f) + EPSV);
        }
        B8 ka[2][2];
#pragma unroll
        for (int MT = 0; MT < 2; ++MT)
#pragma unroll
          for (int ks = 0; ks < 2; ++ks) {
              ka[MT][ks].u[0] = pk2((qa[2*ks+0][MT][0] - mu[MT]) * rs[MT],
                                    (qa[2*ks+0][MT][1] - mu[MT]) * rs[MT]);
              ka[MT][ks].u[1] = pk2((qa[2*ks+0][MT][2] - mu[MT]) * rs[MT],
                                    (qa[2*ks+0][MT][3] - mu[MT]) * rs[MT]);
              ka[MT][ks].u[2] = pk2((qa[2*ks+1][MT][0] - mu[MT]) * rs[MT],
                                    (qa[2*ks+1][MT][1] - mu[MT]) * rs[MT]);
              ka[MT][ks].u[3] = pk2((qa[2*ks+1][MT][2] - mu[MT]) * rs[MT],
                                    (qa[2*ks+1][MT][3] - mu[MT]) * rs[MT]);
          }
#pragma unroll
        for (int MT = 0; MT < 2; ++MT)
#pragma unroll
          for (int nt = 0; nt < 4; ++nt) {
              outa[MT][nt] = MFMA_BF16(ka[MT][0].v, mB[0][nt], outa[MT][nt], 0, 0, 0);
              outa[MT][nt] = MFMA_BF16(ka[MT][1].v, mB[1][nt], outa[MT][nt], 0, 0, 0);
          }
    }

#pragma unroll
    for (int MT = 0; MT < 2; ++MT)
#pragma unroll
      for (int q = 0; q < 4; ++q) {
          float* orow = out + (px0 + 16 * MT + 4 * g + q) * 64;
#pragma unroll
          for (int nt = 0; nt < 4; ++nt)
              orow[16 * nt + m16] = outa[MT][nt][q] + cbv[nt];
      }
}

} // namespace

extern "C" void kernel_launch(void* const* d_in, const int* in_sizes, int n_in,
                              void* d_out, int out_size, void* d_ws, size_t ws_size,
                              hipStream_t stream)
{
    const float* v     = (const float*)d_in[0];
    const float* Wq_w  = (const float*)d_in[1];
    const float* Wq_b  = (const float*)d_in[2];
    const float* Wk_w  = (const float*)d_in[3];
    const float* Wk_b  = (const float*)d_in[4];
    const float* Wv_w  = (const float*)d_in[5];
    const float* Wv_b  = (const float*)d_in[6];
    const float* lnq_g = (const float*)d_in[7];
    const float* lnq_b = (const float*)d_in[8];
    const float* lnk_g = (const float*)d_in[9];
    const float* lnk_b = (const float*)d_in[10];
    const float* Wo_w  = (const float*)d_in[11];
    const float* Wo_b  = (const float*)d_in[12];
    float* out = (float*)d_out;

    float* wsf    = (float*)d_ws;
    float* part   = wsf;                                      // 4*64*8*TILE
    float* s2buf  = part + (size_t)4 * NCH * 8 * TILE;        // 32*8*TILE
    float* cbeta  = s2buf + (size_t)32 * 8 * TILE;            // 256
    unsigned short* base_s = (unsigned short*)(cbeta + 256);
    unsigned short* wkpk   = base_s;
    unsigned short* wvpk   = base_s + 32768;
    unsigned short* wqpk   = base_s + 65536;
    unsigned short* wksumb = base_s + 98304;
    unsigned short* mpk    = base_s + 98816;

    kpack<<<24, 256, 0, stream>>>(Wk_w, Wv_w, Wq_w, wkpk, wvpk, wqpk, wksumb, cbeta);
    ka_kv<<<dim3(NCH, 4), 512, 0, stream>>>(v, wkpk, wvpk, wksumb, Wk_b, Wv_b, part);
    k2a_reduce<<<dim3(8, 32), 256, 0, stream>>>(part, s2buf);
    k2b_mix<<<dim3(8, 4), 256, 0, stream>>>(s2buf, lnk_g, lnk_b, lnq_g, lnq_b,
                                            Wo_w, Wo_b, mpk, cbeta);
    k3_out<<<dim3(128, 4), 256, 0, stream>>>(v, wqpk, Wq_b, mpk, cbeta, out);
}